// Round 9
// baseline (4554.686 us; speedup 1.0000x reference)
//
#include <hip/hip_runtime.h>

// ============================================================================
// Wired CfC (NCP) scan, B=256 x T=1024, 3 layers (hid 135/89/32) + final FC.
//
// Round 9 = round 8 (MFMA rewrite) with the d_ws dependency removed: round 8
// died with "container failed twice" and the only unauditable hazard was
// writing 368 KB of weight fragments into d_ws (unknown ws_size -> possible
// OOB VM fault). Fragments + folded biases now live in static __device__
// arrays (module globals; prep kernels fully rewrite them every call, so
// every launch does identical work -> graph-capture safe).
//
// Design (r8): 16 blocks x 512 thr; block owns 16 batch rows (M=16 exact).
//  - Per tick: 357 MFMAs 16x16x32_f16 (L0 9 ntiles x 7 kt, L1 6 x 8,
//    L2 2 x 4, x3 matrices) -> ~1731 cyc/tick floor -> ~760us.
//  - Weights streamed from L2 every tick (357 KB/CU-tick; <=2 CUs/XCD active
//    so frags stay L2-resident). No reg/LDS weight residency -> no capacity
//    deadlock (r2-r7 lesson: block VGPR total pinned to 65536).
//  - xcat: overlapping-window f16 buffer per parity: [x:0..63 | h0:64..198 |
//    pad | h1:208..296 | h2:297..328 | pad], 16 rows, stride 344 f16.
//    L0 window @0 (7 k-tiles), L1 @64 (8 kt, h1 cols shifted to 144 in the
//    padded-K space), L2 @208 (4 kt). Garbage beyond each true K is nulled
//    by zero-padded weight columns. One h-write serves next layer AND own
//    recurrence. Layer L computes tick-L; 1 barrier/tick.
//  - Wave->triple map WTRI: 17 (L,ntile) triples over 8 waves, 42-45
//    MFMA/wave/tick; all 3 matrices of a triple on one wave (epilogue
//    needs C1,C2,Ca together).
// Predict: 800-1000us, MfmaUtil ~5%, VALUBusy <10%, WRITE <1MB, absmax ~4e-3.
// ============================================================================

typedef _Float16 f16x8 __attribute__((ext_vector_type(8)));
typedef _Float16 f16x4 __attribute__((ext_vector_type(4)));
typedef float    f32x4 __attribute__((ext_vector_type(4)));

#define TSTEPS 1024
#define NROWB  16
#define NBLK   16
#define NTHR   512
#define RSTR   344              // xcat row stride in f16 (688 B = 43*16B)
#define XPAR   (NROWB * RSTR)   // f16 per parity = 5504
#define NFRAG  357

// ---- static device storage (replaces d_ws) ----
__device__ _Float16 g_frag[NFRAG * 512];   // 365568 B of B-fragments
__device__ float    g_B1[256];
__device__ float    g_B2[256];
__device__ float    g_BA[256];

// ---- tables ----
__device__ const int KTt[3]   = {7, 8, 4};       // k-tiles per layer
__device__ const int WINt[3]  = {0, 64, 208};    // A-window start (f16 units)
__device__ const int HIDt[3]  = {135, 89, 32};
__device__ const int UBt[3]   = {0, 135, 224};   // global unit base
__device__ const int SLOTt[3] = {64, 208, 297};  // h output slot in xcat row
__device__ const int KWt[3]   = {199, 224, 121}; // true weight width fin+hid
__device__ const int TLt[17]  = {0,0,0,0,0,0,0,0,0, 1,1,1,1,1,1, 2,2};
__device__ const int TNt[17]  = {0,1,2,3,4,5,6,7,8, 0,1,2,3,4,5, 0,1};
__device__ const int FBASEt[17] = {0,21,42,63,84,105,126,147,168,
                                   189,213,237,261,285,309, 333,345};
__device__ const int WTRI[8][3] = {{0,9,-1},{1,10,-1},{2,11,-1},{3,12,-1},
                                   {4,13,-1},{5,14,-1},{6,7,-1},{8,15,16}};

struct WPtr {
    const float* W1[3]; const float* W2[3];
    const float* Wa[3]; const float* Wb[3];
    const float* b1[3]; const float* b2[3];
    const float* ba[3]; const float* bb[3];
    const unsigned int* mk[3];
};

__device__ __forceinline__ float fexp2(float x) { return __builtin_amdgcn_exp2f(x); }
__device__ __forceinline__ float frcp(float x)  { return __builtin_amdgcn_rcpf(x); }
__device__ __forceinline__ float fsig(float x)  { return frcp(1.0f + fexp2(-1.442695041f * x)); }
__device__ __forceinline__ float ftanh(float x) { return 2.0f * frcp(1.0f + fexp2(-2.885390082f * x)) - 1.0f; }

// ---- prep: pack masked/folded weights into B-fragment layout in g_frag ----
// frag fid (1024 B): lane l holds W[n = ntile*16 + (l&15)][k = kt*32 + (l>>4)*8 + j]
// fid = FBASE[triple] + kt*3 + m, m in {W1, W2, Wa+Wb}
__global__ __launch_bounds__(64) void prep_frags(WPtr P) {
    const int fid = blockIdx.x;
    const int l   = threadIdx.x;
    int t = 0;
    for (int i = 1; i < 17; ++i) if (fid >= FBASEt[i]) t = i;
    const int L = TLt[t], nt = TNt[t];
    const int rem = fid - FBASEt[t];
    const int kt = rem / 3, m = rem - kt * 3;
    const int n  = nt * 16 + (l & 15);
    const bool vn = n < HIDt[L];
    const int KW = KWt[L];
    f16x8 w;
#pragma unroll
    for (int j = 0; j < 8; ++j) {
        const int k = kt * 32 + ((l >> 4) & 3) * 8 + j;
        int ks; bool vk;
        if (L == 1) {  // cols: 0..134 = h0, 144..232 = h1 (shifted +9)
            if (k < 135)                  { ks = k;     vk = true; }
            else if (k >= 144 && k < 233) { ks = k - 9; vk = true; }
            else                          { ks = 0;     vk = false; }
        } else { ks = k; vk = k < KW; }
        float v = 0.f;
        if (vn && vk) {
            const int idx = n * KW + ks;
            if (m == 2)      v = P.Wa[L][idx] + P.Wb[L][idx];
            else if (m == 0) v = P.mk[L][idx] ? P.W1[L][idx] : 0.f;
            else             v = P.mk[L][idx] ? P.W2[L][idx] : 0.f;
        }
        w[j] = (_Float16)v;
    }
    *(f16x8*)(g_frag + (size_t)fid * 512 + l * 8) = w;
}

__global__ __launch_bounds__(256) void prep_bias(WPtr P) {
    const int u = threadIdx.x;
    const int L = (u < 135) ? 0 : ((u < 224) ? 1 : 2);
    const int n = u - UBt[L];
    g_B1[u] = P.b1[L][n];
    g_B2[u] = P.b2[L][n];
    g_BA[u] = P.ba[L][n] + P.bb[L][n];
}

template<int KT>
__device__ __forceinline__ void run_k(const _Float16* ap, const f16x8* bp,
                                      f32x4& d1, f32x4& d2, f32x4& da) {
#pragma unroll
    for (int kt = 0; kt < KT; ++kt) {
        const f16x8 a = *(const f16x8*)(ap + kt * 32);
        d1 = __builtin_amdgcn_mfma_f32_16x16x32_f16(a, bp[(kt * 3 + 0) * 64], d1, 0, 0, 0);
        d2 = __builtin_amdgcn_mfma_f32_16x16x32_f16(a, bp[(kt * 3 + 1) * 64], d2, 0, 0, 0);
        da = __builtin_amdgcn_mfma_f32_16x16x32_f16(a, bp[(kt * 3 + 2) * 64], da, 0, 0, 0);
    }
}

__global__ __launch_bounds__(NTHR) void cfc_main(
        const float* __restrict__ x, const float* __restrict__ fcW,
        const float* __restrict__ fcb, float* __restrict__ out) {
    __shared__ __align__(16) _Float16 xs[2 * XPAR];
    __shared__ __align__(16) float hn[NROWB * 256];

    const int tid  = threadIdx.x;
    const int blk  = blockIdx.x;
    const int wid  = tid >> 6;
    const int l    = tid & 63;
    const int l15  = l & 15;
    const int quad = l >> 4;

    // zero xcat (both parities; pad regions must stay 0)
    for (int i = tid; i < 2 * XPAR / 2; i += NTHR) ((int*)xs)[i] = 0;
    __syncthreads();

    // per-wave triple config (unrolled -> registers)
    const int ntri = (wid == 7) ? 3 : 2;
    int Ls[3], fb[3], slot_[3], ub_[3], win_[3], kt_[3], ncol[3];
    bool vcol[3];
    float bv1[3], bv2[3], bva[3];
#pragma unroll
    for (int ti = 0; ti < 3; ++ti) {
        const int t = WTRI[wid][ti < ntri ? ti : 0];
        const int L = TLt[t];
        Ls[ti] = L; fb[ti] = FBASEt[t]; kt_[ti] = KTt[L];
        slot_[ti] = SLOTt[L]; ub_[ti] = UBt[L]; win_[ti] = WINt[L];
        const int n = TNt[t] * 16 + l15;
        ncol[ti] = n;
        vcol[ti] = n < HIDt[L];
        const int bidx = UBt[L] + (vcol[ti] ? n : 0);
        bv1[ti] = vcol[ti] ? g_B1[bidx] : 0.f;
        bv2[ti] = vcol[ti] ? g_B2[bidx] : 0.f;
        bva[ti] = vcol[ti] ? g_BA[bidx] : 0.f;
    }

    // x staging: threads 0..255, row = tid>>4, kq = tid&15 (4 floats each)
    float4 xpend = {0.f, 0.f, 0.f, 0.f};
    if (tid < 256) {
        const int row = tid >> 4, kq = tid & 15;
        const size_t gbase = ((size_t)(blk * NROWB + row) * TSTEPS) * 64 + kq * 4;
        const float4 x0 = *(const float4*)(x + gbase);           // x(0)
        f16x4 h4;
        h4[0] = (_Float16)x0.x; h4[1] = (_Float16)x0.y;
        h4[2] = (_Float16)x0.z; h4[3] = (_Float16)x0.w;
        *(f16x4*)(xs + row * RSTR + kq * 4) = h4;                // parity 0
        xpend = *(const float4*)(x + gbase + 64);                // x(1)
    }
    const int aoff = l15 * RSTR + quad * 8;  // A-frag: row=l&15, k-sub=quad*8
    __syncthreads();

    // ---- main scan: layer L computes timestep (tick - L); 1 barrier/tick ----
    for (int tick = 0; tick < TSTEPS + 2; ++tick) {
        const int par  = tick & 1;
        const int parn = par ^ 1;

        if (tid < 256) {
            const int row = tid >> 4, kq = tid & 15;
            if (tick + 1 < TSTEPS) {
                f16x4 h4;
                h4[0] = (_Float16)xpend.x; h4[1] = (_Float16)xpend.y;
                h4[2] = (_Float16)xpend.z; h4[3] = (_Float16)xpend.w;
                *(f16x4*)(xs + parn * XPAR + row * RSTR + kq * 4) = h4;
            }
            if (tick + 2 < TSTEPS)
                xpend = *(const float4*)(x + ((size_t)(blk * NROWB + row) * TSTEPS
                                              + tick + 2) * 64 + kq * 4);
        }

        const _Float16* xp = xs + par * XPAR;
#pragma unroll
        for (int ti = 0; ti < 3; ++ti) {
            if (ti < ntri) {
                const int s = tick - Ls[ti];
                if (s >= 0 && s < TSTEPS) {
                    const _Float16* ap = xp + win_[ti] + aoff;
                    const f16x8* bp = (const f16x8*)g_frag + (size_t)fb[ti] * 64 + l;
                    f32x4 d1 = {0.f, 0.f, 0.f, 0.f};
                    f32x4 d2 = {0.f, 0.f, 0.f, 0.f};
                    f32x4 da = {0.f, 0.f, 0.f, 0.f};
                    const int KT = kt_[ti];
                    if (KT == 7)      run_k<7>(ap, bp, d1, d2, da);
                    else if (KT == 8) run_k<8>(ap, bp, d1, d2, da);
                    else              run_k<4>(ap, bp, d1, d2, da);

                    // epilogue: C layout row=quad*4+j (batch row), col=l&15 (unit)
                    _Float16* hdst = xs + parn * XPAR + slot_[ti] + ncol[ti];
                    const bool vz = vcol[ti];
#pragma unroll
                    for (int j = 0; j < 4; ++j) {
                        const float f1 = ftanh(d1[j] + bv1[ti]);
                        const float f2 = ftanh(d2[j] + bv2[ti]);
                        const float tg = fsig(da[j] + bva[ti]);
                        const float h  = f1 + tg * (f2 - f1);
                        const int row  = quad * 4 + j;
                        if (vz) {
                            hdst[row * RSTR] = (_Float16)h;
                            if (s == TSTEPS - 1)
                                hn[row * 256 + ub_[ti] + ncol[ti]] = h;
                        }
                    }
                }
            }
        }
        __syncthreads();
    }

    // ---- FC epilogue: out[row][o] = dot(hn[row], fcW[o]) + fcb[o] ----
    {
        const int o  = tid & 255;
        const int rs = tid >> 8;           // 0/1 -> rows rs*8 .. rs*8+7
        const float4* wr = (const float4*)(fcW + (size_t)o * 256);
        float acc[8];
#pragma unroll
        for (int r = 0; r < 8; ++r) acc[r] = 0.f;
        for (int d = 0; d < 64; ++d) {
            const float4 w = wr[d];
#pragma unroll
            for (int r = 0; r < 8; ++r) {
                const float4 a = *(const float4*)(hn + (rs * 8 + r) * 256 + d * 4);
                acc[r] += a.x * w.x + a.y * w.y + a.z * w.z + a.w * w.w;
            }
        }
        const float bb = fcb[o];
#pragma unroll
        for (int r = 0; r < 8; ++r)
            out[((size_t)blk * NROWB + rs * 8 + r) * 256 + o] = acc[r] + bb;
    }
}

extern "C" void kernel_launch(void* const* d_in, const int* in_sizes, int n_in,
                              void* d_out, int out_size, void* d_ws, size_t ws_size,
                              hipStream_t stream) {
    (void)in_sizes; (void)n_in; (void)out_size; (void)d_ws; (void)ws_size;
    WPtr P;
    const float* x = (const float*)d_in[0];
    for (int ll = 0; ll < 3; ++ll) {
        const int base = 1 + ll * 9;
        P.mk[ll] = (const unsigned int*)d_in[base + 0];
        P.W1[ll] = (const float*)d_in[base + 1];
        P.W2[ll] = (const float*)d_in[base + 2];
        P.Wa[ll] = (const float*)d_in[base + 3];
        P.Wb[ll] = (const float*)d_in[base + 4];
        P.b1[ll] = (const float*)d_in[base + 5];
        P.b2[ll] = (const float*)d_in[base + 6];
        P.ba[ll] = (const float*)d_in[base + 7];
        P.bb[ll] = (const float*)d_in[base + 8];
    }
    const float* fcW = (const float*)d_in[28];
    const float* fcb = (const float*)d_in[29];

    hipLaunchKernelGGL(prep_frags, dim3(NFRAG), dim3(64), 0, stream, P);
    hipLaunchKernelGGL(prep_bias, dim3(1), dim3(256), 0, stream, P);
    hipLaunchKernelGGL(cfc_main, dim3(NBLK), dim3(NTHR), 0, stream,
                       x, fcW, fcb, (float*)d_out);
}